// Round 1
// baseline (180.463 us; speedup 1.0000x reference)
//
#include <hip/hip_runtime.h>

typedef __bf16 bf16x8 __attribute__((ext_vector_type(8)));
typedef __bf16 bf16x4 __attribute__((ext_vector_type(4)));
typedef float  f32x4  __attribute__((ext_vector_type(4)));

#define GLD_LDS16(gsrc, ldst) \
  __builtin_amdgcn_global_load_lds((const __attribute__((address_space(1))) void*)(gsrc), \
                                   (__attribute__((address_space(3))) void*)(ldst), 16, 0, 0)

// ---------------- 1) GroupNorm partial sums ----------------
// x is [4][64][4096]; (b,g) region = 32768 contiguous floats; 256 blocks of 4096 floats each.
__global__ __launch_bounds__(256) void gn_partial_k(const float* __restrict__ x,
                                                    float* __restrict__ partial) {
  __shared__ float red[2][4];
  const int t = threadIdx.x;
  const float4* base = (const float4*)(x + (size_t)blockIdx.x * 4096);
  float s = 0.f, sq = 0.f;
#pragma unroll
  for (int kk = 0; kk < 4; ++kk) {
    float4 v = base[t + kk * 256];
    s  += (v.x + v.y) + (v.z + v.w);
    sq += (v.x * v.x + v.y * v.y) + (v.z * v.z + v.w * v.w);
  }
#pragma unroll
  for (int o = 32; o >= 1; o >>= 1) {
    s  += __shfl_down(s, o, 64);
    sq += __shfl_down(sq, o, 64);
  }
  if ((t & 63) == 0) { red[0][t >> 6] = s; red[1][t >> 6] = sq; }
  __syncthreads();
  if (t == 0) {
    float S  = (red[0][0] + red[0][1]) + (red[0][2] + red[0][3]);
    float SQ = (red[1][0] + red[1][1]) + (red[1][2] + red[1][3]);
    partial[blockIdx.x * 2]     = S;
    partial[blockIdx.x * 2 + 1] = SQ;
  }
}

// ---------------- 2) finalize mean/rstd ----------------
__global__ void gn_final_k(const float* __restrict__ partial, float* __restrict__ stats) {
  const int t = threadIdx.x;
  if (t < 32) {
    float S = 0.f, SQ = 0.f;
#pragma unroll
    for (int i = 0; i < 8; ++i) {
      S  += partial[(t * 8 + i) * 2];
      SQ += partial[(t * 8 + i) * 2 + 1];
    }
    float mean = S * (1.f / 32768.f);
    float var  = SQ * (1.f / 32768.f) - mean * mean;
    stats[t * 2]     = mean;
    stats[t * 2 + 1] = rsqrtf(fmaxf(var, 0.f) + 1e-5f);
  }
}

// ---------------- 3) fused GroupNorm-normalize + QKV 1x1 conv ----------------
// 512 blocks x 192 threads; block = 32 pixels; thread t = output channel t (0..191).
// Writes: Q [b][s][c] bf16 (pre-scaled 1/8), K [b][s][c] bf16,
//         Vt [b][c][s'] bf16 where within each 64-token tile the position is
//         permuted: p = 4*(q&15) + (q>>4)  (so attention PV B-fragments are contiguous).
__global__ __launch_bounds__(192) void qkv_k(const float* __restrict__ x,
                                             const float* __restrict__ stats,
                                             const float* __restrict__ gamma,
                                             const float* __restrict__ beta,
                                             const float* __restrict__ w_qkv,
                                             const float* __restrict__ b_qkv,
                                             __bf16* __restrict__ qo,
                                             __bf16* __restrict__ ko,
                                             __bf16* __restrict__ vto) {
  __shared__ float xn_lds[32 * 65];  // [px][c], pad 65 -> conflict-free
  __shared__ float v_lds[64 * 33];   // [vchan][px], pad 33 -> conflict-free
  const int t  = threadIdx.x;
  const int b  = blockIdx.x >> 7;
  const int s0 = (blockIdx.x & 127) * 32;

  for (int idx = t; idx < 2048; idx += 192) {
    int c = idx >> 5, px = idx & 31;
    float v  = x[((size_t)(b * 64 + c)) * 4096 + s0 + px];
    int   g2 = (b * 8 + (c >> 3)) * 2;
    xn_lds[px * 65 + c] = (v - stats[g2]) * stats[g2 + 1] * gamma[c] + beta[c];
  }
  float4 wr[16];
  const float4* wrow = (const float4*)(w_qkv + t * 64);
#pragma unroll
  for (int i = 0; i < 16; ++i) wr[i] = wrow[i];
  const float bias = b_qkv[t];
  __syncthreads();

  for (int px = 0; px < 32; ++px) {
    const float* xr = &xn_lds[px * 65];  // broadcast reads
    float a0 = bias, a1 = 0.f, a2 = 0.f, a3 = 0.f;
#pragma unroll
    for (int i = 0; i < 16; i += 4) {
      a0 += wr[i    ].x * xr[4*i     ] + wr[i    ].y * xr[4*i +  1] + wr[i    ].z * xr[4*i +  2] + wr[i    ].w * xr[4*i +  3];
      a1 += wr[i + 1].x * xr[4*i +  4] + wr[i + 1].y * xr[4*i +  5] + wr[i + 1].z * xr[4*i +  6] + wr[i + 1].w * xr[4*i +  7];
      a2 += wr[i + 2].x * xr[4*i +  8] + wr[i + 2].y * xr[4*i +  9] + wr[i + 2].z * xr[4*i + 10] + wr[i + 2].w * xr[4*i + 11];
      a3 += wr[i + 3].x * xr[4*i + 12] + wr[i + 3].y * xr[4*i + 13] + wr[i + 3].z * xr[4*i + 14] + wr[i + 3].w * xr[4*i + 15];
    }
    float acc = (a0 + a1) + (a2 + a3);
    if (t < 64)
      qo[((size_t)b * 4096 + s0 + px) * 64 + t] = (__bf16)(acc * 0.125f);  // fold softmax scale
    else if (t < 128)
      ko[((size_t)b * 4096 + s0 + px) * 64 + (t - 64)] = (__bf16)acc;
    else
      v_lds[(t - 128) * 33 + px] = acc;
  }
  __syncthreads();
  // Vt write with per-64 tile permutation (stays within one 128B line per row-chunk).
  for (int u = t; u < 2048; u += 192) {
    int rowc = u >> 5, px = u & 31;
    int qq = (s0 & 63) + px;            // s0 multiple of 32, px<32 -> no carry
    int p  = 4 * (qq & 15) + (qq >> 4); // lambda^{-1}
    vto[((size_t)(b * 64 + rowc)) * 4096 + (s0 & ~63) + p] = (__bf16)v_lds[rowc * 33 + px];
  }
}

// ---------------- 4) flash attention ----------------
// 256 blocks x 128 threads (2 waves). Wave owns 32 Q-rows (2 x 16-row MFMA tiles).
// K/Vt tiles (64 keys) double-buffered in LDS via global_load_lds w=16,
// XOR-swizzled via pre-swizzled global source addresses.
__global__ __launch_bounds__(128) void attn_k(const __bf16* __restrict__ q,
                                              const __bf16* __restrict__ k,
                                              const __bf16* __restrict__ vt,
                                              float* __restrict__ att) {
  __shared__ __bf16 k_lds[2][4096];   // [buf] 64x64, swizzled slots
  __shared__ __bf16 vt_lds[2][4096];  // [buf] 64(d) x 64(p), swizzled slots
  __shared__ __bf16 p_lds[2][2048];   // per-wave 32x64, swizzled
  const int tid  = threadIdx.x;
  const int lane = tid & 63, w = tid >> 6;
  // XCD-aware remap: xcd = blockIdx%8; batch = xcd/2 -> each batch's 2MB K/V pinned to an XCD pair.
  const int pb  = blockIdx.x;
  const int xcd = pb & 7;
  const int b   = xcd >> 1;
  const int q0  = ((pb >> 3) | ((xcd & 1) << 5)) << 6;
  const int row = lane & 15, grp = lane >> 4;
  const __bf16* qb = q  + (size_t)b * 4096 * 64;
  const __bf16* kb = k  + (size_t)b * 4096 * 64;
  const __bf16* vb = vt + (size_t)b * 64 * 4096;

  // Q fragments: A-operand, lane holds Q[l%16][ (l/16)*8 + i ] per 32-wide k-chunk.
  bf16x8 qf[2][2];
#pragma unroll
  for (int rt = 0; rt < 2; ++rt)
#pragma unroll
    for (int kc = 0; kc < 2; ++kc)
      qf[rt][kc] = *(const bf16x8*)(qb + (size_t)(q0 + w * 32 + rt * 16 + row) * 64 + kc * 32 + grp * 8);

  f32x4 acc[2][4];
  float m[2][4], l[2][4];
#pragma unroll
  for (int rt = 0; rt < 2; ++rt)
#pragma unroll
    for (int r = 0; r < 4; ++r) { m[rt][r] = -1e30f; l[rt][r] = 0.f; }
#pragma unroll
  for (int rt = 0; rt < 2; ++rt)
#pragma unroll
    for (int dt = 0; dt < 4; ++dt) acc[rt][dt] = (f32x4){0.f, 0.f, 0.f, 0.f};

  auto stage = [&](int buf, int j0) {
#pragma unroll
    for (int c = 0; c < 4; ++c) {
      int off = tid * 16 + c * 2048;   // byte offset in 8KB tile
      int j = off >> 7;
      int s = (off >> 4) & 7;
      int dc = s ^ (j & 7);            // pre-swizzled source d-chunk
      GLD_LDS16(kb + (size_t)(j0 + j) * 64 + dc * 8, (char*)(&k_lds[buf][0]) + off);
    }
#pragma unroll
    for (int c = 0; c < 4; ++c) {
      int off = tid * 16 + c * 2048;
      int d = off >> 7;
      int s = (off >> 4) & 7;
      int pc = s ^ (d & 7);            // pre-swizzled source p-chunk
      GLD_LDS16(vb + (size_t)d * 4096 + j0 + pc * 8, (char*)(&vt_lds[buf][0]) + off);
    }
  };

  int cur = 0;
  stage(0, 0);
  __syncthreads();
  char* const pbase = (char*)&p_lds[w][0];

  for (int kt = 0; kt < 64; ++kt) {
    if (kt < 63) stage(cur ^ 1, (kt + 1) << 6);  // async prefetch next tile
    const char* kbase = (const char*)&k_lds[cur][0];
    const char* vbase = (const char*)&vt_lds[cur][0];

    // S = Q K^T  (scale pre-folded into Q)
    f32x4 sa[2][4];
#pragma unroll
    for (int rt = 0; rt < 2; ++rt)
#pragma unroll
      for (int jt = 0; jt < 4; ++jt) sa[rt][jt] = (f32x4){0.f, 0.f, 0.f, 0.f};
#pragma unroll
    for (int jt = 0; jt < 4; ++jt) {
      int j = jt * 16 + row;
#pragma unroll
      for (int kc = 0; kc < 2; ++kc) {
        int off = (j << 7) + (((kc * 4 + grp) ^ (j & 7)) << 4);
        bf16x8 bfr = *(const bf16x8*)(kbase + off);
        sa[0][jt] = __builtin_amdgcn_mfma_f32_16x16x32_bf16(qf[0][kc], bfr, sa[0][jt], 0, 0, 0);
        sa[1][jt] = __builtin_amdgcn_mfma_f32_16x16x32_bf16(qf[1][kc], bfr, sa[1][jt], 0, 0, 0);
      }
    }

    // online softmax; write P packed (4 adjacent permuted cols per lane) to LDS
#pragma unroll
    for (int rt = 0; rt < 2; ++rt) {
#pragma unroll
      for (int r = 0; r < 4; ++r) {
        float tmax = fmaxf(fmaxf(sa[rt][0][r], sa[rt][1][r]), fmaxf(sa[rt][2][r], sa[rt][3][r]));
#pragma unroll
        for (int o = 1; o < 16; o <<= 1) tmax = fmaxf(tmax, __shfl_xor(tmax, o, 64));
        float mn = fmaxf(m[rt][r], tmax);
        float sf = __expf(m[rt][r] - mn);
        m[rt][r] = mn;
        float p0 = __expf(sa[rt][0][r] - mn);
        float p1 = __expf(sa[rt][1][r] - mn);
        float p2 = __expf(sa[rt][2][r] - mn);
        float p3 = __expf(sa[rt][3][r] - mn);
        float rs = (p0 + p1) + (p2 + p3);
#pragma unroll
        for (int o = 1; o < 16; o <<= 1) rs += __shfl_xor(rs, o, 64);
        l[rt][r] = l[rt][r] * sf + rs;
#pragma unroll
        for (int dt = 0; dt < 4; ++dt) acc[rt][dt][r] *= sf;
        int rr = rt * 16 + grp * 4 + r;
        bf16x4 pv = { (__bf16)p0, (__bf16)p1, (__bf16)p2, (__bf16)p3 };
        *(bf16x4*)(pbase + ((rr << 7) + ((row << 3) ^ ((rr & 7) << 4)))) = pv;
      }
    }
    asm volatile("s_waitcnt lgkmcnt(0)" ::: "memory");

    // O += P V  (k-index runs over permuted physical positions, matches Vt layout)
#pragma unroll
    for (int kc = 0; kc < 2; ++kc) {
      bf16x8 af[2];
#pragma unroll
      for (int rt = 0; rt < 2; ++rt) {
        int rA = rt * 16 + row;
        af[rt] = *(const bf16x8*)(pbase + ((rA << 7) + ((((kc << 2) + grp) ^ (rA & 7)) << 4)));
      }
#pragma unroll
      for (int dt = 0; dt < 4; ++dt) {
        int d = dt * 16 + row;
        bf16x8 bfr = *(const bf16x8*)(vbase + ((d << 7) + ((((kc << 2) + grp) ^ (d & 7)) << 4)));
        acc[0][dt] = __builtin_amdgcn_mfma_f32_16x16x32_bf16(af[0], bfr, acc[0][dt], 0, 0, 0);
        acc[1][dt] = __builtin_amdgcn_mfma_f32_16x16x32_bf16(af[1], bfr, acc[1][dt], 0, 0, 0);
      }
    }
    __syncthreads();
    cur ^= 1;
  }

  // epilogue: att[b][s][c] = O / l
#pragma unroll
  for (int rt = 0; rt < 2; ++rt) {
    float* ab = att + ((size_t)b * 4096 + q0 + w * 32 + rt * 16) * 64;
#pragma unroll
    for (int r = 0; r < 4; ++r) {
      float inv = 1.f / l[rt][r];
      int rr = grp * 4 + r;
#pragma unroll
      for (int dt = 0; dt < 4; ++dt)
        ab[rr * 64 + dt * 16 + row] = acc[rt][dt][r] * inv;
    }
  }
}

// ---------------- 5) proj 1x1 conv + residual ----------------
// 256 blocks x 256 threads; block = 64 pixels; lane = out channel; LDS transpose for
// coalesced channel-major output.
__global__ __launch_bounds__(256) void proj_k(const float* __restrict__ att,
                                              const float* __restrict__ x,
                                              const float* __restrict__ w_proj,
                                              const float* __restrict__ b_proj,
                                              float* __restrict__ out) {
  __shared__ float a_lds[64 * 65];
  __shared__ float o_lds[64 * 65];
  const int t  = threadIdx.x;
  const int b  = blockIdx.x >> 6;
  const int s0 = (blockIdx.x & 63) * 64;
  for (int idx = t; idx < 4096; idx += 256) {
    int px = idx >> 6, c = idx & 63;
    a_lds[px * 65 + c] = att[((size_t)b * 4096 + s0 + px) * 64 + c];
  }
  const int o = t & 63, wg = t >> 6;
  float4 wr[16];
  const float4* wrow = (const float4*)(w_proj + o * 64);
#pragma unroll
  for (int i = 0; i < 16; ++i) wr[i] = wrow[i];
  const float bias = b_proj[o];
  __syncthreads();
  for (int pp = 0; pp < 16; ++pp) {
    int px = wg * 16 + pp;
    const float* ar = &a_lds[px * 65];
    float a0 = bias, a1 = 0.f, a2 = 0.f, a3 = 0.f;
#pragma unroll
    for (int i = 0; i < 16; i += 4) {
      a0 += wr[i    ].x * ar[4*i     ] + wr[i    ].y * ar[4*i +  1] + wr[i    ].z * ar[4*i +  2] + wr[i    ].w * ar[4*i +  3];
      a1 += wr[i + 1].x * ar[4*i +  4] + wr[i + 1].y * ar[4*i +  5] + wr[i + 1].z * ar[4*i +  6] + wr[i + 1].w * ar[4*i +  7];
      a2 += wr[i + 2].x * ar[4*i +  8] + wr[i + 2].y * ar[4*i +  9] + wr[i + 2].z * ar[4*i + 10] + wr[i + 2].w * ar[4*i + 11];
      a3 += wr[i + 3].x * ar[4*i + 12] + wr[i + 3].y * ar[4*i + 13] + wr[i + 3].z * ar[4*i + 14] + wr[i + 3].w * ar[4*i + 15];
    }
    o_lds[o * 65 + px] = (a0 + a1) + (a2 + a3);
  }
  __syncthreads();
  for (int idx = t; idx < 4096; idx += 256) {
    int c = idx >> 6, px = idx & 63;
    size_t gi = ((size_t)(b * 64 + c)) * 4096 + s0 + px;
    out[gi] = o_lds[c * 65 + px] + x[gi];
  }
}

// ---------------- launch ----------------
extern "C" void kernel_launch(void* const* d_in, const int* in_sizes, int n_in,
                              void* d_out, int out_size, void* d_ws, size_t ws_size,
                              hipStream_t stream) {
  const float* x      = (const float*)d_in[0];
  const float* gamma  = (const float*)d_in[1];
  const float* beta   = (const float*)d_in[2];
  const float* w_qkv  = (const float*)d_in[3];
  const float* b_qkv  = (const float*)d_in[4];
  const float* w_proj = (const float*)d_in[5];
  const float* b_proj = (const float*)d_in[6];
  float* out = (float*)d_out;

  char* ws = (char*)d_ws;
  float*  partial = (float*)ws;                 // 512 f32
  float*  stats   = partial + 512;              // 64 f32
  __bf16* qb  = (__bf16*)(ws + 4096);           // 4*4096*64 bf16 = 2MB
  __bf16* kb  = qb  + (size_t)4 * 4096 * 64;    // 2MB
  __bf16* vtb = kb  + (size_t)4 * 4096 * 64;    // 2MB
  float*  attb = (float*)(vtb + (size_t)4 * 4096 * 64);  // 4MB

  gn_partial_k<<<256, 256, 0, stream>>>(x, partial);
  gn_final_k<<<1, 64, 0, stream>>>(partial, stats);
  qkv_k<<<512, 192, 0, stream>>>(x, stats, gamma, beta, w_qkv, b_qkv, qb, kb, vtb);
  attn_k<<<256, 128, 0, stream>>>(qb, kb, vtb, attb);
  proj_k<<<256, 256, 0, stream>>>(attb, x, w_proj, b_proj, out);
}

// Round 2
// 120.395 us; speedup vs baseline: 1.4989x; 1.4989x over previous
//
#include <hip/hip_runtime.h>

typedef __bf16 bf16x8 __attribute__((ext_vector_type(8)));
typedef __bf16 bf16x4 __attribute__((ext_vector_type(4)));
typedef float  f32x4  __attribute__((ext_vector_type(4)));

// ---------------- 1) GroupNorm partial sums ----------------
// x is [4][64][4096]; (b,g) region = 32768 contiguous floats; 256 blocks of 4096 floats each.
__global__ __launch_bounds__(256) void gn_partial_k(const float* __restrict__ x,
                                                    float* __restrict__ partial) {
  __shared__ float red[2][4];
  const int t = threadIdx.x;
  const float4* base = (const float4*)(x + (size_t)blockIdx.x * 4096);
  float s = 0.f, sq = 0.f;
#pragma unroll
  for (int kk = 0; kk < 4; ++kk) {
    float4 v = base[t + kk * 256];
    s  += (v.x + v.y) + (v.z + v.w);
    sq += (v.x * v.x + v.y * v.y) + (v.z * v.z + v.w * v.w);
  }
#pragma unroll
  for (int o = 32; o >= 1; o >>= 1) {
    s  += __shfl_down(s, o, 64);
    sq += __shfl_down(sq, o, 64);
  }
  if ((t & 63) == 0) { red[0][t >> 6] = s; red[1][t >> 6] = sq; }
  __syncthreads();
  if (t == 0) {
    float S  = (red[0][0] + red[0][1]) + (red[0][2] + red[0][3]);
    float SQ = (red[1][0] + red[1][1]) + (red[1][2] + red[1][3]);
    partial[blockIdx.x * 2]     = S;
    partial[blockIdx.x * 2 + 1] = SQ;
  }
}

// ---------------- 2) finalize mean/rstd ----------------
__global__ void gn_final_k(const float* __restrict__ partial, float* __restrict__ stats) {
  const int t = threadIdx.x;
  if (t < 32) {
    float S = 0.f, SQ = 0.f;
#pragma unroll
    for (int i = 0; i < 8; ++i) {
      S  += partial[(t * 8 + i) * 2];
      SQ += partial[(t * 8 + i) * 2 + 1];
    }
    float mean = S * (1.f / 32768.f);
    float var  = SQ * (1.f / 32768.f) - mean * mean;
    stats[t * 2]     = mean;
    stats[t * 2 + 1] = rsqrtf(fmaxf(var, 0.f) + 1e-5f);
  }
}

// ---------------- 3) fused GroupNorm-normalize + QKV 1x1 conv ----------------
// 512 blocks x 192 threads; block = 32 pixels; thread t = output channel t (0..191).
// Writes: Q [b][s][c] bf16 (pre-scaled 1/8), K [b][s][c] bf16, Vt [b][c][s] bf16 (plain transpose).
__global__ __launch_bounds__(192) void qkv_k(const float* __restrict__ x,
                                             const float* __restrict__ stats,
                                             const float* __restrict__ gamma,
                                             const float* __restrict__ beta,
                                             const float* __restrict__ w_qkv,
                                             const float* __restrict__ b_qkv,
                                             __bf16* __restrict__ qo,
                                             __bf16* __restrict__ ko,
                                             __bf16* __restrict__ vto) {
  __shared__ float xn_lds[32 * 65];  // [px][c], pad 65 -> conflict-free
  __shared__ float v_lds[64 * 33];   // [vchan][px], pad 33 -> conflict-free
  const int t  = threadIdx.x;
  const int b  = blockIdx.x >> 7;
  const int s0 = (blockIdx.x & 127) * 32;

  for (int idx = t; idx < 2048; idx += 192) {
    int c = idx >> 5, px = idx & 31;
    float v  = x[((size_t)(b * 64 + c)) * 4096 + s0 + px];
    int   g2 = (b * 8 + (c >> 3)) * 2;
    xn_lds[px * 65 + c] = (v - stats[g2]) * stats[g2 + 1] * gamma[c] + beta[c];
  }
  float4 wr[16];
  const float4* wrow = (const float4*)(w_qkv + t * 64);
#pragma unroll
  for (int i = 0; i < 16; ++i) wr[i] = wrow[i];
  const float bias = b_qkv[t];
  __syncthreads();

  for (int px = 0; px < 32; ++px) {
    const float* xr = &xn_lds[px * 65];  // broadcast reads
    float a0 = bias, a1 = 0.f, a2 = 0.f, a3 = 0.f;
#pragma unroll
    for (int i = 0; i < 16; i += 4) {
      a0 += wr[i    ].x * xr[4*i     ] + wr[i    ].y * xr[4*i +  1] + wr[i    ].z * xr[4*i +  2] + wr[i    ].w * xr[4*i +  3];
      a1 += wr[i + 1].x * xr[4*i +  4] + wr[i + 1].y * xr[4*i +  5] + wr[i + 1].z * xr[4*i +  6] + wr[i + 1].w * xr[4*i +  7];
      a2 += wr[i + 2].x * xr[4*i +  8] + wr[i + 2].y * xr[4*i +  9] + wr[i + 2].z * xr[4*i + 10] + wr[i + 2].w * xr[4*i + 11];
      a3 += wr[i + 3].x * xr[4*i + 12] + wr[i + 3].y * xr[4*i + 13] + wr[i + 3].z * xr[4*i + 14] + wr[i + 3].w * xr[4*i + 15];
    }
    float acc = (a0 + a1) + (a2 + a3);
    if (t < 64)
      qo[((size_t)b * 4096 + s0 + px) * 64 + t] = (__bf16)(acc * 0.125f);  // fold softmax scale
    else if (t < 128)
      ko[((size_t)b * 4096 + s0 + px) * 64 + (t - 64)] = (__bf16)acc;
    else
      v_lds[(t - 128) * 33 + px] = acc;
  }
  __syncthreads();
  for (int u = t; u < 2048; u += 192) {
    int rowc = u >> 5, px = u & 31;
    vto[((size_t)(b * 64 + rowc)) * 4096 + s0 + px] = (__bf16)v_lds[rowc * 33 + px];
  }
}

// ---------------- 4) flash attention, split-K, swapped-QK^T, no K/V staging ----------------
// 2048 blocks x 128 threads (2 independent waves; NO barriers in the k-loop).
// Block = (batch, 64 q-rows, key-segment of 512). Wave = 32 q-rows (2 x 16-row tiles).
// S^T = mfma(A=K, B=Q): lane owns 16 key-scores of ONE q-row -> in-lane softmax,
// 2 shfls per tile for the max, l is a per-lane partial reduced once at epilogue.
// P^T exchanged through per-wave LDS (XOR-swizzled), V^T read straight from global (L2-hot).
__global__ __launch_bounds__(128) void attn_k(const __bf16* __restrict__ q,
                                              const __bf16* __restrict__ k,
                                              const __bf16* __restrict__ vt,
                                              float* __restrict__ opart,
                                              float* __restrict__ mlpart) {
  __shared__ __bf16 p_lds[2][32 * 64];  // per-wave P^T tile [qrow][key], key-XOR swizzled
  const int tid  = threadIdx.x;
  const int lane = tid & 63, w = tid >> 6;
  const int row  = lane & 15, grp = lane >> 4;

  // XCD-aware remap: batch pinned to an XCD pair -> its 1MB K/V stays L2-resident.
  const int blk  = blockIdx.x;
  const int xcd  = blk & 7;
  const int b    = xcd >> 1;
  const int rest = blk >> 3;                      // 0..255
  const int seg  = rest >> 5;                     // 0..7
  const int qb   = (rest & 31) | ((xcd & 1) << 5);// 0..63
  const int q0   = qb * 64 + w * 32;              // this wave's 32 q-rows
  const int j0b  = seg * 512;

  const __bf16* qp = q  + (size_t)b * 4096 * 64;
  const __bf16* kp = k  + (size_t)b * 4096 * 64;
  const __bf16* vp = vt + (size_t)b * 64 * 4096;

  // Q as B-operand: lane holds Q[qrow=lane&15][grp*8..+7 (+32kc)] — same bytes as A-layout.
  bf16x8 qf[2][2];
#pragma unroll
  for (int rt = 0; rt < 2; ++rt)
#pragma unroll
    for (int kc = 0; kc < 2; ++kc)
      qf[rt][kc] = *(const bf16x8*)(qp + (size_t)(q0 + rt * 16 + row) * 64 + kc * 32 + grp * 8);

  f32x4 acc[2][4];
#pragma unroll
  for (int rt = 0; rt < 2; ++rt)
#pragma unroll
    for (int dt = 0; dt < 4; ++dt) acc[rt][dt] = (f32x4){0.f, 0.f, 0.f, 0.f};
  float m[2] = {-1e30f, -1e30f}, l[2] = {0.f, 0.f};

  char* const pbase = (char*)&p_lds[w][0];
  const int swz = (row & 7) << 3;  // key-index XOR, spreads the 128B-stride rows across banks

  for (int kt = 0; kt < 8; ++kt) {
    const int j0 = j0b + kt * 64;

    // S^T[key][qrow] = K · Q^T   (softmax scale pre-folded into Q)
    f32x4 sa[2][4];
#pragma unroll
    for (int rt = 0; rt < 2; ++rt)
#pragma unroll
      for (int jt = 0; jt < 4; ++jt) sa[rt][jt] = (f32x4){0.f, 0.f, 0.f, 0.f};
#pragma unroll
    for (int jt = 0; jt < 4; ++jt) {
      const __bf16* kr = kp + (size_t)(j0 + jt * 16 + row) * 64 + grp * 8;
      bf16x8 kf0 = *(const bf16x8*)(kr);
      bf16x8 kf1 = *(const bf16x8*)(kr + 32);
      sa[0][jt] = __builtin_amdgcn_mfma_f32_16x16x32_bf16(kf0, qf[0][0], sa[0][jt], 0, 0, 0);
      sa[1][jt] = __builtin_amdgcn_mfma_f32_16x16x32_bf16(kf0, qf[1][0], sa[1][jt], 0, 0, 0);
      sa[0][jt] = __builtin_amdgcn_mfma_f32_16x16x32_bf16(kf1, qf[0][1], sa[0][jt], 0, 0, 0);
      sa[1][jt] = __builtin_amdgcn_mfma_f32_16x16x32_bf16(kf1, qf[1][1], sa[1][jt], 0, 0, 0);
    }

    // online softmax: lane owns 16 of the 64 keys for its q-row
#pragma unroll
    for (int rt = 0; rt < 2; ++rt) {
      float t0 = fmaxf(fmaxf(sa[rt][0][0], sa[rt][0][1]), fmaxf(sa[rt][0][2], sa[rt][0][3]));
      float t1 = fmaxf(fmaxf(sa[rt][1][0], sa[rt][1][1]), fmaxf(sa[rt][1][2], sa[rt][1][3]));
      float t2 = fmaxf(fmaxf(sa[rt][2][0], sa[rt][2][1]), fmaxf(sa[rt][2][2], sa[rt][2][3]));
      float t3 = fmaxf(fmaxf(sa[rt][3][0], sa[rt][3][1]), fmaxf(sa[rt][3][2], sa[rt][3][3]));
      float tmax = fmaxf(fmaxf(t0, t1), fmaxf(t2, t3));
      tmax = fmaxf(tmax, __shfl_xor(tmax, 16, 64));
      tmax = fmaxf(tmax, __shfl_xor(tmax, 32, 64));
      float mn = fmaxf(m[rt], tmax);
      float sf = __expf(m[rt] - mn);
      m[rt] = mn;
      float ls = 0.f;
#pragma unroll
      for (int jt = 0; jt < 4; ++jt) {
        float p0 = __expf(sa[rt][jt][0] - mn);
        float p1 = __expf(sa[rt][jt][1] - mn);
        float p2 = __expf(sa[rt][jt][2] - mn);
        float p3 = __expf(sa[rt][jt][3] - mn);
        ls += (p0 + p1) + (p2 + p3);
        bf16x4 pv = {(__bf16)p0, (__bf16)p1, (__bf16)p2, (__bf16)p3};
        // P^T[qrow][key= grp*4 + r + 16*jt], swizzled
        *(bf16x4*)(pbase + ((rt * 16 + row) << 7) + ((((grp << 2) + (jt << 4)) ^ swz) << 1)) = pv;
      }
      l[rt] = l[rt] * sf + ls;          // per-lane partial sum; reduced at epilogue
#pragma unroll
      for (int dt = 0; dt < 4; ++dt) {
        acc[rt][dt][0] *= sf; acc[rt][dt][1] *= sf;
        acc[rt][dt][2] *= sf; acc[rt][dt][3] *= sf;
      }
    }
    asm volatile("s_waitcnt lgkmcnt(0)" ::: "memory");  // per-wave P visibility (no barrier)

    // O^T += V^T · P^T  (A = V^T straight from global, B = P^T from LDS)
#pragma unroll
    for (int kc = 0; kc < 2; ++kc) {
      const int koff = (((kc << 5) + (grp << 3)) ^ swz) << 1;
      bf16x8 af0 = *(const bf16x8*)(pbase + (row << 7) + koff);
      bf16x8 af1 = *(const bf16x8*)(pbase + ((16 + row) << 7) + koff);
#pragma unroll
      for (int dt = 0; dt < 4; ++dt) {
        bf16x8 vf = *(const bf16x8*)(vp + (size_t)(dt * 16 + row) * 4096 + j0 + kc * 32 + grp * 8);
        acc[0][dt] = __builtin_amdgcn_mfma_f32_16x16x32_bf16(vf, af0, acc[0][dt], 0, 0, 0);
        acc[1][dt] = __builtin_amdgcn_mfma_f32_16x16x32_bf16(vf, af1, acc[1][dt], 0, 0, 0);
      }
    }
  }

  // epilogue: store UN-normalized O^T + (m, l) for the split-K combine
#pragma unroll
  for (int rt = 0; rt < 2; ++rt) {
    float lt = l[rt];
    lt += __shfl_xor(lt, 16, 64);
    lt += __shfl_xor(lt, 32, 64);
    const int qrow = q0 + rt * 16 + row;
    float* ob = opart + ((size_t)(b * 8 + seg) * 4096 + qrow) * 64;
#pragma unroll
    for (int dt = 0; dt < 4; ++dt)
      *(f32x4*)(ob + dt * 16 + grp * 4) = acc[rt][dt];
    if (grp == 0) {
      float2 mlv; mlv.x = m[rt]; mlv.y = lt;
      *(float2*)(mlpart + ((size_t)(b * 8 + seg) * 4096 + qrow) * 2) = mlv;
    }
  }
}

// ---------------- 5) split-K combine + proj 1x1 conv + residual ----------------
// 512 blocks x 256 threads; block = 32 pixels.
__global__ __launch_bounds__(256) void proj_k(const float* __restrict__ opart,
                                              const float* __restrict__ mlpart,
                                              const float* __restrict__ x,
                                              const float* __restrict__ w_proj,
                                              const float* __restrict__ b_proj,
                                              float* __restrict__ out) {
  __shared__ float wseg[8][32];
  __shared__ float a_lds[32 * 68];  // stride 68: float4-aligned + bank-rotating
  __shared__ float o_lds[64 * 33];
  const int t  = threadIdx.x;
  const int b  = blockIdx.x >> 7;
  const int s0 = (blockIdx.x & 127) * 32;

  if (t < 32) {
    const int rowg = s0 + t;
    float ms[8], ls[8], es[8];
    float M = -1e30f;
#pragma unroll
    for (int s = 0; s < 8; ++s) {
      float2 ml = *(const float2*)(mlpart + ((size_t)(b * 8 + s) * 4096 + rowg) * 2);
      ms[s] = ml.x; ls[s] = ml.y;
      M = fmaxf(M, ms[s]);
    }
    float L = 0.f;
#pragma unroll
    for (int s = 0; s < 8; ++s) { es[s] = __expf(ms[s] - M); L += es[s] * ls[s]; }
    float invL = 1.f / L;
#pragma unroll
    for (int s = 0; s < 8; ++s) wseg[s][t] = es[s] * invL;
  }
  __syncthreads();

  // weighted combine of the 8 segment partials -> a_lds[px][c]
  for (int i = t; i < 512; i += 256) {
    const int px = i >> 4, c4 = i & 15;
    const float* obase = opart + ((size_t)(b * 8) * 4096 + s0 + px) * 64 + c4 * 4;
    float4 a = {0.f, 0.f, 0.f, 0.f};
#pragma unroll
    for (int s = 0; s < 8; ++s) {
      float4 v = *(const float4*)(obase + (size_t)s * 4096 * 64);
      float wv = wseg[s][px];
      a.x += wv * v.x; a.y += wv * v.y; a.z += wv * v.z; a.w += wv * v.w;
    }
    *(float4*)(&a_lds[px * 68 + c4 * 4]) = a;
  }

  const int o = t & 63, wg = t >> 6;
  float4 wr[16];
  const float4* wrow = (const float4*)(w_proj + o * 64);
#pragma unroll
  for (int i = 0; i < 16; ++i) wr[i] = wrow[i];
  const float bias = b_proj[o];
  __syncthreads();

  for (int pp = 0; pp < 8; ++pp) {
    const int px = wg * 8 + pp;
    const float* ar = &a_lds[px * 68];
    float a0 = bias, a1 = 0.f, a2 = 0.f, a3 = 0.f;
#pragma unroll
    for (int i = 0; i < 16; i += 4) {
      a0 += wr[i    ].x * ar[4*i     ] + wr[i    ].y * ar[4*i +  1] + wr[i    ].z * ar[4*i +  2] + wr[i    ].w * ar[4*i +  3];
      a1 += wr[i + 1].x * ar[4*i +  4] + wr[i + 1].y * ar[4*i +  5] + wr[i + 1].z * ar[4*i +  6] + wr[i + 1].w * ar[4*i +  7];
      a2 += wr[i + 2].x * ar[4*i +  8] + wr[i + 2].y * ar[4*i +  9] + wr[i + 2].z * ar[4*i + 10] + wr[i + 2].w * ar[4*i + 11];
      a3 += wr[i + 3].x * ar[4*i + 12] + wr[i + 3].y * ar[4*i + 13] + wr[i + 3].z * ar[4*i + 14] + wr[i + 3].w * ar[4*i + 15];
    }
    o_lds[o * 33 + px] = (a0 + a1) + (a2 + a3);
  }
  __syncthreads();
  for (int idx = t; idx < 2048; idx += 256) {
    const int c = idx >> 5, px = idx & 31;
    const size_t gi = ((size_t)(b * 64 + c)) * 4096 + s0 + px;
    out[gi] = o_lds[c * 33 + px] + x[gi];
  }
}

// ---------------- launch ----------------
extern "C" void kernel_launch(void* const* d_in, const int* in_sizes, int n_in,
                              void* d_out, int out_size, void* d_ws, size_t ws_size,
                              hipStream_t stream) {
  const float* x      = (const float*)d_in[0];
  const float* gamma  = (const float*)d_in[1];
  const float* beta   = (const float*)d_in[2];
  const float* w_qkv  = (const float*)d_in[3];
  const float* b_qkv  = (const float*)d_in[4];
  const float* w_proj = (const float*)d_in[5];
  const float* b_proj = (const float*)d_in[6];
  float* out = (float*)d_out;

  char* ws = (char*)d_ws;
  float*  partial = (float*)ws;                         // 512 f32
  float*  stats   = partial + 512;                      // 64 f32
  __bf16* qb  = (__bf16*)(ws + 4096);                   // 2MB
  __bf16* kb  = qb  + (size_t)4 * 4096 * 64;            // 2MB
  __bf16* vtb = kb  + (size_t)4 * 4096 * 64;            // 2MB
  float*  opart = (float*)(vtb + (size_t)4 * 4096 * 64);        // 4*8*4096*64 f32 = 32MB
  float*  mlpart = opart + (size_t)4 * 8 * 4096 * 64;           // 4*8*4096*2 f32 = 1MB

  gn_partial_k<<<256, 256, 0, stream>>>(x, partial);
  gn_final_k<<<1, 64, 0, stream>>>(partial, stats);
  qkv_k<<<512, 192, 0, stream>>>(x, stats, gamma, beta, w_qkv, b_qkv, qb, kb, vtb);
  attn_k<<<2048, 128, 0, stream>>>(qb, kb, vtb, opart, mlpart);
  proj_k<<<512, 256, 0, stream>>>(opart, mlpart, x, w_proj, b_proj, out);
}

// Round 3
// 102.851 us; speedup vs baseline: 1.7546x; 1.1706x over previous
//
#include <hip/hip_runtime.h>

typedef __bf16 bf16x8 __attribute__((ext_vector_type(8)));
typedef __bf16 bf16x4 __attribute__((ext_vector_type(4)));
typedef float  f32x4  __attribute__((ext_vector_type(4)));

#define GLD_LDS16(gsrc, ldst) \
  __builtin_amdgcn_global_load_lds((const __attribute__((address_space(1))) void*)(gsrc), \
                                   (__attribute__((address_space(3))) void*)(ldst), 16, 0, 0)

// ---------------- 1) GroupNorm partial sums ----------------
__global__ __launch_bounds__(256) void gn_partial_k(const float* __restrict__ x,
                                                    float* __restrict__ partial) {
  __shared__ float red[2][4];
  const int t = threadIdx.x;
  const float4* base = (const float4*)(x + (size_t)blockIdx.x * 4096);
  float s = 0.f, sq = 0.f;
#pragma unroll
  for (int kk = 0; kk < 4; ++kk) {
    float4 v = base[t + kk * 256];
    s  += (v.x + v.y) + (v.z + v.w);
    sq += (v.x * v.x + v.y * v.y) + (v.z * v.z + v.w * v.w);
  }
#pragma unroll
  for (int o = 32; o >= 1; o >>= 1) {
    s  += __shfl_down(s, o, 64);
    sq += __shfl_down(sq, o, 64);
  }
  if ((t & 63) == 0) { red[0][t >> 6] = s; red[1][t >> 6] = sq; }
  __syncthreads();
  if (t == 0) {
    float S  = (red[0][0] + red[0][1]) + (red[0][2] + red[0][3]);
    float SQ = (red[1][0] + red[1][1]) + (red[1][2] + red[1][3]);
    partial[blockIdx.x * 2]     = S;
    partial[blockIdx.x * 2 + 1] = SQ;
  }
}

// ---------------- 2) finalize mean/rstd ----------------
__global__ void gn_final_k(const float* __restrict__ partial, float* __restrict__ stats) {
  const int t = threadIdx.x;
  if (t < 32) {
    float S = 0.f, SQ = 0.f;
#pragma unroll
    for (int i = 0; i < 8; ++i) {
      S  += partial[(t * 8 + i) * 2];
      SQ += partial[(t * 8 + i) * 2 + 1];
    }
    float mean = S * (1.f / 32768.f);
    float var  = SQ * (1.f / 32768.f) - mean * mean;
    stats[t * 2]     = mean;
    stats[t * 2 + 1] = rsqrtf(fmaxf(var, 0.f) + 1e-5f);
  }
}

// ---------------- 3) fused GroupNorm-normalize + QKV 1x1 conv ----------------
__global__ __launch_bounds__(192) void qkv_k(const float* __restrict__ x,
                                             const float* __restrict__ stats,
                                             const float* __restrict__ gamma,
                                             const float* __restrict__ beta,
                                             const float* __restrict__ w_qkv,
                                             const float* __restrict__ b_qkv,
                                             __bf16* __restrict__ qo,
                                             __bf16* __restrict__ ko,
                                             __bf16* __restrict__ vto) {
  __shared__ float xn_lds[32 * 65];
  __shared__ float v_lds[64 * 33];
  const int t  = threadIdx.x;
  const int b  = blockIdx.x >> 7;
  const int s0 = (blockIdx.x & 127) * 32;

  for (int idx = t; idx < 2048; idx += 192) {
    int c = idx >> 5, px = idx & 31;
    float v  = x[((size_t)(b * 64 + c)) * 4096 + s0 + px];
    int   g2 = (b * 8 + (c >> 3)) * 2;
    xn_lds[px * 65 + c] = (v - stats[g2]) * stats[g2 + 1] * gamma[c] + beta[c];
  }
  float4 wr[16];
  const float4* wrow = (const float4*)(w_qkv + t * 64);
#pragma unroll
  for (int i = 0; i < 16; ++i) wr[i] = wrow[i];
  const float bias = b_qkv[t];
  __syncthreads();

  for (int px = 0; px < 32; ++px) {
    const float* xr = &xn_lds[px * 65];
    float a0 = bias, a1 = 0.f, a2 = 0.f, a3 = 0.f;
#pragma unroll
    for (int i = 0; i < 16; i += 4) {
      a0 += wr[i    ].x * xr[4*i     ] + wr[i    ].y * xr[4*i +  1] + wr[i    ].z * xr[4*i +  2] + wr[i    ].w * xr[4*i +  3];
      a1 += wr[i + 1].x * xr[4*i +  4] + wr[i + 1].y * xr[4*i +  5] + wr[i + 1].z * xr[4*i +  6] + wr[i + 1].w * xr[4*i +  7];
      a2 += wr[i + 2].x * xr[4*i +  8] + wr[i + 2].y * xr[4*i +  9] + wr[i + 2].z * xr[4*i + 10] + wr[i + 2].w * xr[4*i + 11];
      a3 += wr[i + 3].x * xr[4*i + 12] + wr[i + 3].y * xr[4*i + 13] + wr[i + 3].z * xr[4*i + 14] + wr[i + 3].w * xr[4*i + 15];
    }
    float acc = (a0 + a1) + (a2 + a3);
    if (t < 64)
      qo[((size_t)b * 4096 + s0 + px) * 64 + t] = (__bf16)(acc * 0.125f);
    else if (t < 128)
      ko[((size_t)b * 4096 + s0 + px) * 64 + (t - 64)] = (__bf16)acc;
    else
      v_lds[(t - 128) * 33 + px] = acc;
  }
  __syncthreads();
  for (int u = t; u < 2048; u += 192) {
    int rowc = u >> 5, px = u & 31;
    vto[((size_t)(b * 64 + rowc)) * 4096 + s0 + px] = (__bf16)v_lds[rowc * 33 + px];
  }
}

// ---------------- 4) flash attention: LDS-staged K/V, 1-deep pipeline ----------------
// 1024 blocks x 256 threads (4 waves). Block = (batch, seg of 512 keys, 128 q-rows).
// Wave = 32 q-rows. K/V tiles double-buffered in LDS via global_load_lds w=16 with
// pre-swizzled global source (conflict-free ds_read_b128). Prefetch of tile kt+1 is
// issued BEFORE compute of kt; one vmcnt(0)+barrier per iter. Swapped QK^T softmax.
__global__ __launch_bounds__(256, 3) void attn_k(const __bf16* __restrict__ q,
                                                 const __bf16* __restrict__ k,
                                                 const __bf16* __restrict__ vt,
                                                 __bf16* __restrict__ opart,
                                                 float* __restrict__ mlpart) {
  __shared__ __bf16 k_lds[2][4096];   // 64 keys x 64 d, swizzled slots
  __shared__ __bf16 v_lds[2][4096];   // 64 d x 64 keys, swizzled slots
  __shared__ __bf16 p_lds[4][2048];   // per-wave P^T 32 x 64, swizzled
  const int tid  = threadIdx.x;
  const int lane = tid & 63, w = tid >> 6;
  const int row  = lane & 15, grp = lane >> 4;

  // XCD-aware decode: batch pinned to an XCD pair.
  const int blk  = blockIdx.x;
  const int xcd  = blk & 7;
  const int b    = xcd >> 1;
  const int rest = blk >> 3;                        // 0..127
  const int seg  = rest >> 4;                       // 0..7
  const int qblk = (rest & 15) | ((xcd & 1) << 4);  // 0..31
  const int q0   = qblk * 128 + w * 32;
  const int j0b  = seg * 512;

  const __bf16* qp = q  + (size_t)b * 4096 * 64;
  const __bf16* kp = k  + (size_t)b * 4096 * 64;
  const __bf16* vp = vt + (size_t)b * 64 * 4096;

  bf16x8 qf[2][2];
#pragma unroll
  for (int rt = 0; rt < 2; ++rt)
#pragma unroll
    for (int kc = 0; kc < 2; ++kc)
      qf[rt][kc] = *(const bf16x8*)(qp + (size_t)(q0 + rt * 16 + row) * 64 + kc * 32 + grp * 8);

  f32x4 acc[2][4];
#pragma unroll
  for (int rt = 0; rt < 2; ++rt)
#pragma unroll
    for (int dt = 0; dt < 4; ++dt) acc[rt][dt] = (f32x4){0.f, 0.f, 0.f, 0.f};
  float m[2] = {-1e30f, -1e30f}, l[2] = {0.f, 0.f};

  // staging offsets (constant per thread): 2 rounds of 4KB per 8KB tile
  const int soff0 = tid * 16, soff1 = tid * 16 + 4096;
  const int sj0 = soff0 >> 7, sj1 = soff1 >> 7;             // row within tile
  const int sc0 = ((soff0 >> 4) & 7) ^ (sj0 & 7);           // pre-swizzled chunk
  const int sc1 = ((soff1 >> 4) & 7) ^ (sj1 & 7);

  auto stage = [&](int buf, int j0) {
    GLD_LDS16(kp + (size_t)(j0 + sj0) * 64 + sc0 * 8, (char*)(&k_lds[buf][0]) + soff0);
    GLD_LDS16(kp + (size_t)(j0 + sj1) * 64 + sc1 * 8, (char*)(&k_lds[buf][0]) + soff1);
    GLD_LDS16(vp + (size_t)sj0 * 4096 + j0 + sc0 * 8, (char*)(&v_lds[buf][0]) + soff0);
    GLD_LDS16(vp + (size_t)sj1 * 4096 + j0 + sc1 * 8, (char*)(&v_lds[buf][0]) + soff1);
  };

  stage(0, j0b);
  asm volatile("s_waitcnt vmcnt(0)" ::: "memory");
  __syncthreads();

  char* const pbase = (char*)&p_lds[w][0];
  const int swz = (row & 7) << 3;

#pragma unroll
  for (int kt = 0; kt < 8; ++kt) {
    const int cur = kt & 1;
    if (kt < 7) stage(cur ^ 1, j0b + (kt + 1) * 64);  // prefetch next tile (stays in flight)

    const char* kbase = (const char*)&k_lds[cur][0];
    const char* vbase = (const char*)&v_lds[cur][0];

    // S^T = K · Q^T (scale folded into Q); ds_read_b128 conflict-free via swizzle
    f32x4 sa[2][4];
#pragma unroll
    for (int rt = 0; rt < 2; ++rt)
#pragma unroll
      for (int jt = 0; jt < 4; ++jt) sa[rt][jt] = (f32x4){0.f, 0.f, 0.f, 0.f};
    __builtin_amdgcn_s_setprio(1);
#pragma unroll
    for (int jt = 0; jt < 4; ++jt) {
      const int jr = jt * 16 + row;
      bf16x8 kf0 = *(const bf16x8*)(kbase + jr * 128 + ((grp ^ (row & 7)) << 4));
      bf16x8 kf1 = *(const bf16x8*)(kbase + jr * 128 + (((4 + grp) ^ (row & 7)) << 4));
      sa[0][jt] = __builtin_amdgcn_mfma_f32_16x16x32_bf16(kf0, qf[0][0], sa[0][jt], 0, 0, 0);
      sa[1][jt] = __builtin_amdgcn_mfma_f32_16x16x32_bf16(kf0, qf[1][0], sa[1][jt], 0, 0, 0);
      sa[0][jt] = __builtin_amdgcn_mfma_f32_16x16x32_bf16(kf1, qf[0][1], sa[0][jt], 0, 0, 0);
      sa[1][jt] = __builtin_amdgcn_mfma_f32_16x16x32_bf16(kf1, qf[1][1], sa[1][jt], 0, 0, 0);
    }
    __builtin_amdgcn_s_setprio(0);

    // online softmax (lane owns 16 keys of one q-row)
#pragma unroll
    for (int rt = 0; rt < 2; ++rt) {
      float t0 = fmaxf(fmaxf(sa[rt][0][0], sa[rt][0][1]), fmaxf(sa[rt][0][2], sa[rt][0][3]));
      float t1 = fmaxf(fmaxf(sa[rt][1][0], sa[rt][1][1]), fmaxf(sa[rt][1][2], sa[rt][1][3]));
      float t2 = fmaxf(fmaxf(sa[rt][2][0], sa[rt][2][1]), fmaxf(sa[rt][2][2], sa[rt][2][3]));
      float t3 = fmaxf(fmaxf(sa[rt][3][0], sa[rt][3][1]), fmaxf(sa[rt][3][2], sa[rt][3][3]));
      float tmax = fmaxf(fmaxf(t0, t1), fmaxf(t2, t3));
      tmax = fmaxf(tmax, __shfl_xor(tmax, 16, 64));
      tmax = fmaxf(tmax, __shfl_xor(tmax, 32, 64));
      float mn = fmaxf(m[rt], tmax);
      float sf = __expf(m[rt] - mn);
      m[rt] = mn;
      float ls = 0.f;
#pragma unroll
      for (int jt = 0; jt < 4; ++jt) {
        float p0 = __expf(sa[rt][jt][0] - mn);
        float p1 = __expf(sa[rt][jt][1] - mn);
        float p2 = __expf(sa[rt][jt][2] - mn);
        float p3 = __expf(sa[rt][jt][3] - mn);
        ls += (p0 + p1) + (p2 + p3);
        bf16x4 pv = {(__bf16)p0, (__bf16)p1, (__bf16)p2, (__bf16)p3};
        *(bf16x4*)(pbase + ((rt * 16 + row) << 7) + ((((grp << 2) + (jt << 4)) ^ swz) << 1)) = pv;
      }
      l[rt] = l[rt] * sf + ls;
#pragma unroll
      for (int dt = 0; dt < 4; ++dt) {
        acc[rt][dt][0] *= sf; acc[rt][dt][1] *= sf;
        acc[rt][dt][2] *= sf; acc[rt][dt][3] *= sf;
      }
    }
    asm volatile("s_waitcnt lgkmcnt(0)" ::: "memory");  // own-wave P visibility

    // O^T += V^T · P^T
    __builtin_amdgcn_s_setprio(1);
#pragma unroll
    for (int kc = 0; kc < 2; ++kc) {
      const int koff = (((kc << 5) + (grp << 3)) ^ swz) << 1;
      bf16x8 af0 = *(const bf16x8*)(pbase + (row << 7) + koff);
      bf16x8 af1 = *(const bf16x8*)(pbase + ((16 + row) << 7) + koff);
#pragma unroll
      for (int dt = 0; dt < 4; ++dt) {
        const int dr = dt * 16 + row;
        bf16x8 vf = *(const bf16x8*)(vbase + dr * 128 + ((((kc << 2) + grp) ^ (row & 7)) << 4));
        acc[0][dt] = __builtin_amdgcn_mfma_f32_16x16x32_bf16(vf, af0, acc[0][dt], 0, 0, 0);
        acc[1][dt] = __builtin_amdgcn_mfma_f32_16x16x32_bf16(vf, af1, acc[1][dt], 0, 0, 0);
      }
    }
    __builtin_amdgcn_s_setprio(0);

    asm volatile("s_waitcnt vmcnt(0)" ::: "memory");  // next tile landed
    __syncthreads();                                   // all waves: safe to reuse buffers
  }

  // epilogue: un-normalized O^T (bf16) + (m, l) for split-K combine
#pragma unroll
  for (int rt = 0; rt < 2; ++rt) {
    float lt = l[rt];
    lt += __shfl_xor(lt, 16, 64);
    lt += __shfl_xor(lt, 32, 64);
    const int qrow = q0 + rt * 16 + row;
    __bf16* ob = opart + ((size_t)(b * 8 + seg) * 4096 + qrow) * 64;
#pragma unroll
    for (int dt = 0; dt < 4; ++dt) {
      bf16x4 ov = {(__bf16)acc[rt][dt][0], (__bf16)acc[rt][dt][1],
                   (__bf16)acc[rt][dt][2], (__bf16)acc[rt][dt][3]};
      *(bf16x4*)(ob + dt * 16 + grp * 4) = ov;
    }
    if (grp == 0) {
      float2 mlv; mlv.x = m[rt]; mlv.y = lt;
      *(float2*)(mlpart + ((size_t)(b * 8 + seg) * 4096 + qrow) * 2) = mlv;
    }
  }
}

// ---------------- 5) split-K combine + proj 1x1 conv + residual ----------------
__global__ __launch_bounds__(256) void proj_k(const __bf16* __restrict__ opart,
                                              const float* __restrict__ mlpart,
                                              const float* __restrict__ x,
                                              const float* __restrict__ w_proj,
                                              const float* __restrict__ b_proj,
                                              float* __restrict__ out) {
  __shared__ float wseg[8][32];
  __shared__ float a_lds[32 * 68];
  __shared__ float o_lds[64 * 33];
  const int t  = threadIdx.x;
  const int b  = blockIdx.x >> 7;
  const int s0 = (blockIdx.x & 127) * 32;

  if (t < 32) {
    const int rowg = s0 + t;
    float ms[8], ls[8], es[8];
    float M = -1e30f;
#pragma unroll
    for (int s = 0; s < 8; ++s) {
      float2 ml = *(const float2*)(mlpart + ((size_t)(b * 8 + s) * 4096 + rowg) * 2);
      ms[s] = ml.x; ls[s] = ml.y;
      M = fmaxf(M, ms[s]);
    }
    float L = 0.f;
#pragma unroll
    for (int s = 0; s < 8; ++s) { es[s] = __expf(ms[s] - M); L += es[s] * ls[s]; }
    float invL = 1.f / L;
#pragma unroll
    for (int s = 0; s < 8; ++s) wseg[s][t] = es[s] * invL;
  }
  __syncthreads();

  for (int i = t; i < 512; i += 256) {
    const int px = i >> 4, c4 = i & 15;
    const __bf16* obase = opart + ((size_t)(b * 8) * 4096 + s0 + px) * 64 + c4 * 4;
    float4 a = {0.f, 0.f, 0.f, 0.f};
#pragma unroll
    for (int s = 0; s < 8; ++s) {
      bf16x4 v = *(const bf16x4*)(obase + (size_t)s * 4096 * 64);
      float wv = wseg[s][px];
      a.x += wv * (float)v[0]; a.y += wv * (float)v[1];
      a.z += wv * (float)v[2]; a.w += wv * (float)v[3];
    }
    *(float4*)(&a_lds[px * 68 + c4 * 4]) = a;
  }

  const int o = t & 63, wg = t >> 6;
  float4 wr[16];
  const float4* wrow = (const float4*)(w_proj + o * 64);
#pragma unroll
  for (int i = 0; i < 16; ++i) wr[i] = wrow[i];
  const float bias = b_proj[o];
  __syncthreads();

  for (int pp = 0; pp < 8; ++pp) {
    const int px = wg * 8 + pp;
    const float* ar = &a_lds[px * 68];
    float a0 = bias, a1 = 0.f, a2 = 0.f, a3 = 0.f;
#pragma unroll
    for (int i = 0; i < 16; i += 4) {
      a0 += wr[i    ].x * ar[4*i     ] + wr[i    ].y * ar[4*i +  1] + wr[i    ].z * ar[4*i +  2] + wr[i    ].w * ar[4*i +  3];
      a1 += wr[i + 1].x * ar[4*i +  4] + wr[i + 1].y * ar[4*i +  5] + wr[i + 1].z * ar[4*i +  6] + wr[i + 1].w * ar[4*i +  7];
      a2 += wr[i + 2].x * ar[4*i +  8] + wr[i + 2].y * ar[4*i +  9] + wr[i + 2].z * ar[4*i + 10] + wr[i + 2].w * ar[4*i + 11];
      a3 += wr[i + 3].x * ar[4*i + 12] + wr[i + 3].y * ar[4*i + 13] + wr[i + 3].z * ar[4*i + 14] + wr[i + 3].w * ar[4*i + 15];
    }
    o_lds[o * 33 + px] = (a0 + a1) + (a2 + a3);
  }
  __syncthreads();
  for (int idx = t; idx < 2048; idx += 256) {
    const int c = idx >> 5, px = idx & 31;
    const size_t gi = ((size_t)(b * 64 + c)) * 4096 + s0 + px;
    out[gi] = o_lds[c * 33 + px] + x[gi];
  }
}

// ---------------- launch ----------------
extern "C" void kernel_launch(void* const* d_in, const int* in_sizes, int n_in,
                              void* d_out, int out_size, void* d_ws, size_t ws_size,
                              hipStream_t stream) {
  const float* x      = (const float*)d_in[0];
  const float* gamma  = (const float*)d_in[1];
  const float* beta   = (const float*)d_in[2];
  const float* w_qkv  = (const float*)d_in[3];
  const float* b_qkv  = (const float*)d_in[4];
  const float* w_proj = (const float*)d_in[5];
  const float* b_proj = (const float*)d_in[6];
  float* out = (float*)d_out;

  char* ws = (char*)d_ws;
  float*  partial = (float*)ws;                          // 512 f32
  float*  stats   = partial + 512;                       // 64 f32
  __bf16* qb  = (__bf16*)(ws + 4096);                    // 2MB
  __bf16* kb  = qb  + (size_t)4 * 4096 * 64;             // 2MB
  __bf16* vtb = kb  + (size_t)4 * 4096 * 64;             // 2MB
  __bf16* opart = vtb + (size_t)4 * 4096 * 64;           // 4*8*4096*64 bf16 = 16MB
  float*  mlpart = (float*)(opart + (size_t)4 * 8 * 4096 * 64);  // 1MB

  gn_partial_k<<<256, 256, 0, stream>>>(x, partial);
  gn_final_k<<<1, 64, 0, stream>>>(partial, stats);
  qkv_k<<<512, 192, 0, stream>>>(x, stats, gamma, beta, w_qkv, b_qkv, qb, kb, vtb);
  attn_k<<<1024, 256, 0, stream>>>(qb, kb, vtb, opart, mlpart);
  proj_k<<<512, 256, 0, stream>>>(opart, mlpart, x, w_proj, b_proj, out);
}